// Round 3
// baseline (895.312 us; speedup 1.0000x reference)
//
#include <hip/hip_runtime.h>
#include <hip/hip_bf16.h>

#define B_    16
#define C_    96
#define H_    224
#define W_    224
#define COUT_ 96
#define GH_   14
#define GW_   14
#define P_    196          // GH_*GW_
#define HW_   (H_*W_)      // 50176

typedef __attribute__((ext_vector_type(8))) unsigned short ushort8;
typedef __attribute__((ext_vector_type(8))) short        short8;   // MFMA bf16x8 operand
typedef __attribute__((ext_vector_type(4))) float        f32x4;

__device__ __forceinline__ unsigned short f2bf(float f) {
    union { __hip_bfloat16 h; unsigned short u; } cv;
    cv.h = __float2bfloat16(f);
    return cv.u;
}

// ---------------------------------------------------------------------------
// Kernel 0: output_filters (COUT, C, 3, 3) f32 -> ofb[tap][cout][c] bf16
// ---------------------------------------------------------------------------
__global__ __launch_bounds__(256) void prep_ofb(const float* __restrict__ of,
                                                unsigned short* __restrict__ ofb) {
    int idx = blockIdx.x * 256 + threadIdx.x;      // 9*96*96 = 82944
    if (idx < 9 * 96 * 96) {
        int tap = idx / (96 * 96);
        int r   = idx % (96 * 96);
        int cout = r / 96, c = r % 96;
        ofb[idx] = f2bf(of[((size_t)cout * 96 + c) * 9 + tap]);
    }
}

// ---------------------------------------------------------------------------
// Fused kernel: per-patch depthwise 3x3 (recomputed incl. 18x18 halo from
// neighbor patches) -> bf16 LDS tile -> implicit-GEMM MFMA dense 3x3 -> GELU.
// Block = (b, patch), 256 threads / 4 waves. 32-channel groups keep LDS small.
//
// Halo sa pixel (oy,ox): owner patch = (oy>>4, ox>>4); patch-local clip uses
// (oy&15, ox&15). Image-OOB halo pixels are zero (conv2's zero padding).
// ---------------------------------------------------------------------------
__global__ __launch_bounds__(256, 3) void fused_kernel(
        const float* __restrict__ x,
        const float* __restrict__ pf,
        const unsigned short* __restrict__ ofb,
        float* __restrict__ out) {
    // XCD-aware swizzle (3136 % 8 == 0 -> bijective)
    int bid0 = blockIdx.x;
    int bid  = (bid0 % 8) * (3136 / 8) + bid0 / 8;
    int patch = bid % P_;
    int b     = bid / P_;
    int gh = patch / GW_, gw = patch % GW_;
    int y0 = gh * 16, x0 = gw * 16;

    int t = threadIdx.x;
    int w = t >> 6, l = t & 63;
    int mrow = l & 15, kgrp = l >> 4;

    // LDS: 25920 + 13440 + 2592 = 41952 B -> 3 blocks/CU
    __shared__ unsigned short at[324 * 40];   // halo sa tile, 32 ch + 8 pad (80 B rows)
    __shared__ float xs[8 * 20 * 21];         // x staging: 8 ch x 20 rows x 20 cols (+1 pad)
    __shared__ float pfs[8][9][9];            // patch filters: 8 ch x 9 neighbor patches x 9 taps

    f32x4 acc[4][6];
    #pragma unroll
    for (int mi = 0; mi < 4; ++mi)
        #pragma unroll
        for (int ni = 0; ni < 6; ++ni)
            acc[mi][ni] = (f32x4)0.f;

    #pragma unroll 1
    for (int g = 0; g < 3; ++g) {
        // ---- build 32-ch halo tile in 4 chunks of 8 channels ----
        #pragma unroll 1
        for (int cc = 0; cc < 4; ++cc) {
            int c0 = g * 32 + cc * 8;
            __syncthreads();   // xs/pfs reuse; first iter also guards atile vs prev MFMA

            // stage x halo (20x20, zero-padded at image edge) for 8 channels
            for (int v = t; v < 3200; v += 256) {
                int ch = v / 400, rem = v % 400;
                int row = rem / 20, col = rem % 20;
                int gy = y0 - 2 + row, gx = x0 - 2 + col;
                float val = 0.f;
                if (gy >= 0 && gy < H_ && gx >= 0 && gx < W_)
                    val = x[((size_t)(b * 96 + c0 + ch) * H_ + gy) * W_ + gx];
                xs[ch * 420 + row * 21 + col] = val;
            }
            // stage depthwise filters for the 3x3 neighborhood of patches
            for (int v = t; v < 648; v += 256) {
                int ch = v / 81, rem = v % 81;
                int p9 = rem / 9, tap = rem % 9;
                int gh2 = gh + p9 / 3 - 1, gw2 = gw + p9 % 3 - 1;
                float val = 0.f;
                if (gh2 >= 0 && gh2 < GH_ && gw2 >= 0 && gw2 < GW_)
                    val = pf[((size_t)(c0 + ch) * P_ + gh2 * GW_ + gw2) * 9 + tap];
                pfs[ch][p9][tap] = val;
            }
            __syncthreads();

            // depthwise conv: 324 halo px x 8 ch
            for (int task = t; task < 2592; task += 256) {
                int ch = task & 7, hpx = task >> 3;
                int r = hpx / 18 - 1, c = hpx % 18 - 1;
                int oy = y0 + r, ox = x0 + c;
                unsigned short val = 0;
                if (oy >= 0 && oy < H_ && ox >= 0 && ox < W_) {
                    int py = oy & 15, px = ox & 15;
                    int p9 = ((oy >> 4) - gh + 1) * 3 + ((ox >> 4) - gw + 1);
                    const float* fw = &pfs[ch][p9][0];
                    float a = 0.f;
                    #pragma unroll
                    for (int dy = -1; dy <= 1; ++dy) {
                        if ((unsigned)(py + dy) < 16u) {
                            #pragma unroll
                            for (int dx = -1; dx <= 1; ++dx) {
                                if ((unsigned)(px + dx) < 16u)
                                    a = fmaf(xs[ch * 420 + (r + dy + 2) * 21 + (c + dx + 2)],
                                             fw[(dy + 1) * 3 + (dx + 1)], a);
                            }
                        }
                    }
                    val = f2bf(a);
                }
                at[hpx * 40 + cc * 8 + ch] = val;
            }
        }
        __syncthreads();

        // ---- MFMA: 9 taps, K=32 for this channel group ----
        #pragma unroll 1
        for (int tap = 0; tap < 9; ++tap) {
            int ky = tap / 3, kx = tap % 3;
            short8 af[4];
            #pragma unroll
            for (int mi = 0; mi < 4; ++mi)
                af[mi] = *(const short8*)&at[((w * 4 + mi + ky) * 18 + kx + mrow) * 40 + kgrp * 8];
            const unsigned short* bofs = ofb + tap * (96 * 96) + g * 32 + kgrp * 8;
            #pragma unroll
            for (int ni = 0; ni < 6; ++ni) {
                short8 bf = *(const short8*)&bofs[(ni * 16 + mrow) * 96];
                #pragma unroll
                for (int mi = 0; mi < 4; ++mi)
                    acc[mi][ni] = __builtin_amdgcn_mfma_f32_16x16x32_bf16(
                        af[mi], bf, acc[mi][ni], 0, 0, 0);
            }
        }
    }

    // ---- epilogue: exact GELU + f32x4 stores ----
    #pragma unroll
    for (int mi = 0; mi < 4; ++mi) {
        int gy = y0 + w * 4 + mi;
        #pragma unroll
        for (int ni = 0; ni < 6; ++ni) {
            int cout = ni * 16 + mrow;
            f32x4 gv;
            #pragma unroll
            for (int j = 0; j < 4; ++j) {
                float v = acc[mi][ni][j];
                gv[j] = 0.5f * v * (1.0f + erff(v * 0.70710678118f));
            }
            *(f32x4*)&out[((size_t)b * COUT_ + cout) * HW_ + (size_t)gy * W_ +
                          x0 + kgrp * 4] = gv;
        }
    }
}

extern "C" void kernel_launch(void* const* d_in, const int* in_sizes, int n_in,
                              void* d_out, int out_size, void* d_ws, size_t ws_size,
                              hipStream_t stream) {
    const float* x  = (const float*)d_in[0];
    const float* pf = (const float*)d_in[1];
    const float* of = (const float*)d_in[2];
    float* out = (float*)d_out;

    unsigned short* ofb = (unsigned short*)d_ws;   // 165,888 B

    prep_ofb<<<324, 256, 0, stream>>>(of, ofb);
    fused_kernel<<<B_ * P_, 256, 0, stream>>>(x, pf, ofb, out);
}

// Round 5
// 464.130 us; speedup vs baseline: 1.9290x; 1.9290x over previous
//
#include <hip/hip_runtime.h>
#include <hip/hip_bf16.h>

#define B_    16
#define C_    96
#define H_    224
#define W_    224
#define COUT_ 96
#define GH_   14
#define GW_   14
#define P_    196          // GH_*GW_
#define HW_   (H_*W_)      // 50176
#define NCH_  12           // 8-channel chunks

typedef __attribute__((ext_vector_type(8))) unsigned short ushort8;
typedef __attribute__((ext_vector_type(8))) short        short8;   // MFMA bf16x8 operand
typedef __attribute__((ext_vector_type(4))) float        f32x4;

__device__ __forceinline__ unsigned short f2bf(float f) {
    union { __hip_bfloat16 h; unsigned short u; } cv;
    cv.h = __float2bfloat16(f);
    return cv.u;
}

// ---------------------------------------------------------------------------
// Kernel 0: output_filters (COUT, C, 3, 3) f32 -> ofb[tap][cout][c] bf16
// ---------------------------------------------------------------------------
__global__ __launch_bounds__(256) void prep_ofb(const float* __restrict__ of,
                                                unsigned short* __restrict__ ofb) {
    int idx = blockIdx.x * 256 + threadIdx.x;      // 9*96*96 = 82944
    if (idx < 9 * 96 * 96) {
        int tap = idx / (96 * 96);
        int r   = idx % (96 * 96);
        int cout = r / 96, c = r % 96;
        ofb[idx] = f2bf(of[((size_t)cout * 96 + c) * 9 + tap]);
    }
}

// ---------------------------------------------------------------------------
// Kernel 1: per-patch depthwise 3x3 (patch-local zero padding).
// x: (B,C,H,W) f32 -> sa: (B, 12, H, W, 8) bf16  (8-ch chunk planes).
// Block = (b,patch), thread = pixel. 16 KB dbuf LDS, 1 barrier/chunk,
// next chunk's global loads issued under current chunk's compute.
// ---------------------------------------------------------------------------
__global__ __launch_bounds__(256) void sa_kernel(const float* __restrict__ x,
                                                 const float* __restrict__ pf,
                                                 unsigned short* __restrict__ sa) {
    int bid   = blockIdx.x;
    int patch = bid % P_;
    int b     = bid / P_;
    int gh = patch / GW_, gw = patch % GW_;
    int t  = threadIdx.x;
    int py = t >> 4, px = t & 15;
    int y  = gh * 16 + py, xx = gw * 16 + px;

    __shared__ float xs[2][8][256];    // 16 KB double-buffered x slice

    const float* xp0 = x + (size_t)b * C_ * HW_ + (size_t)y * W_ + xx;

    float lf[8];
    #pragma unroll
    for (int ch = 0; ch < 8; ++ch) lf[ch] = xp0[(size_t)ch * HW_];

    for (int cc = 0; cc < NCH_; ++cc) {
        int buf = cc & 1;
        #pragma unroll
        for (int ch = 0; ch < 8; ++ch) xs[buf][ch][t] = lf[ch];
        __syncthreads();
        if (cc < NCH_ - 1) {
            #pragma unroll
            for (int ch = 0; ch < 8; ++ch)
                lf[ch] = xp0[(size_t)((cc + 1) * 8 + ch) * HW_];
        }

        ushort8 v;
        #pragma unroll
        for (int ch = 0; ch < 8; ++ch) {
            const float* wgt = pf + ((size_t)(cc * 8 + ch) * P_ + patch) * 9;  // uniform -> s_load
            float a = 0.f;
            #pragma unroll
            for (int dy = -1; dy <= 1; ++dy) {
                int yy = py + dy;
                if ((unsigned)yy < 16u) {
                    #pragma unroll
                    for (int dx = -1; dx <= 1; ++dx) {
                        int xq = px + dx;
                        if ((unsigned)xq < 16u)
                            a = fmaf(xs[buf][ch][yy * 16 + xq],
                                     wgt[(dy + 1) * 3 + (dx + 1)], a);
                    }
                }
            }
            v[ch] = f2bf(a);
        }
        // lanes consecutive in x -> 16 B/lane fully coalesced
        *(ushort8*)&sa[(((size_t)(b * NCH_ + cc) * H_ + y) * W_ + xx) * 8] = v;
    }
}

// ---------------------------------------------------------------------------
// Kernel 2: dense 3x3 conv as implicit GEMM (M=256 px, N=96, K=864) + GELU.
// sa: (B,12,H,W,8) bf16; ofb: [tap][cout][c] bf16; out: (B,COUT,H,W) f32.
// Per 32-ch group: reg-stage halo tile -> padded LDS (stride 40 ushorts),
// double-buffered; next group's loads issued under current group's MFMA.
// ---------------------------------------------------------------------------
__global__ __launch_bounds__(256) void conv2_mfma(const unsigned short* __restrict__ sa,
                                                  const unsigned short* __restrict__ ofb,
                                                  float* __restrict__ out) {
    // XCD-aware swizzle (3136 % 8 == 0 -> bijective)
    int bid0 = blockIdx.x;
    int bid  = (bid0 % 8) * (3136 / 8) + bid0 / 8;
    int patch = bid % P_;
    int b     = bid / P_;
    int gh = patch / GW_, gw = patch % GW_;
    int y0 = gh * 16, x0 = gw * 16;

    int t = threadIdx.x;
    int w = t >> 6, l = t & 63;
    int mrow = l & 15, kgrp = l >> 4;

    __shared__ ushort8 at8[2][1620];        // 2 x 324 px x 40 ushort = 51840 B

    ushort8 r[6];                           // staged tiles in flight (24 VGPR)

    // ---- load one 32-ch group's 18x18 halo (4 chunk-planes) into regs ----
    auto LOADG = [&](int g) {
        #pragma unroll
        for (int i = 0; i < 6; ++i) {
            int v = t + i * 256;            // 1296 tasks = 4 chunks x 324 px
            if (v < 1296) {
                int ccl = v / 324, hpx = v % 324;
                int gy = y0 - 1 + hpx / 18, gx = x0 - 1 + hpx % 18;
                ushort8 val = {0, 0, 0, 0, 0, 0, 0, 0};
                if ((unsigned)gy < (unsigned)H_ && (unsigned)gx < (unsigned)W_)
                    val = *(const ushort8*)&sa[(((size_t)(b * NCH_ + g * 4 + ccl) * H_ + gy)
                                               * W_ + gx) * 8];
                r[i] = val;
            }
        }
    };
    auto WRITEG = [&](int g) {
        unsigned short* atw = (unsigned short*)at8[g & 1];
        #pragma unroll
        for (int i = 0; i < 6; ++i) {
            int v = t + i * 256;
            if (v < 1296) {
                int ccl = v / 324, hpx = v % 324;
                *(ushort8*)&atw[hpx * 40 + ccl * 8] = r[i];
            }
        }
    };

    f32x4 acc[4][6];
    #pragma unroll
    for (int mi = 0; mi < 4; ++mi)
        #pragma unroll
        for (int ni = 0; ni < 6; ++ni)
            acc[mi][ni] = (f32x4)0.f;

    LOADG(0);
    #pragma unroll 1
    for (int g = 0; g < 3; ++g) {
        WRITEG(g);                          // waits (auto vmcnt) on LOADG(g)
        __syncthreads();                    // tile g visible to all waves
        if (g < 2) LOADG(g + 1);            // overlap next loads with MFMA
        const unsigned short* atg = (const unsigned short*)at8[g & 1];

        #pragma unroll 1
        for (int tap = 0; tap < 9; ++tap) {
            int ky = tap / 3, kx = tap % 3;
            short8 af[4];
            #pragma unroll
            for (int mi = 0; mi < 4; ++mi)
                af[mi] = *(const short8*)&atg[((w * 4 + mi + ky) * 18 + kx + mrow) * 40
                                              + kgrp * 8];
            const unsigned short* bofs = ofb + tap * (96 * 96) + g * 32 + kgrp * 8;
            #pragma unroll
            for (int ni = 0; ni < 6; ++ni) {
                short8 bf = *(const short8*)&bofs[(ni * 16 + mrow) * 96];
                #pragma unroll
                for (int mi = 0; mi < 4; ++mi)
                    acc[mi][ni] = __builtin_amdgcn_mfma_f32_16x16x32_bf16(
                        af[mi], bf, acc[mi][ni], 0, 0, 0);
            }
        }
    }

    // ---- epilogue: exact GELU + f32x4 stores (identical to R2, verified) ----
    #pragma unroll
    for (int mi = 0; mi < 4; ++mi) {
        int gy = y0 + w * 4 + mi;
        #pragma unroll
        for (int ni = 0; ni < 6; ++ni) {
            int cout = ni * 16 + mrow;
            f32x4 gv;
            #pragma unroll
            for (int j = 0; j < 4; ++j) {
                float vv = acc[mi][ni][j];
                gv[j] = 0.5f * vv * (1.0f + erff(vv * 0.70710678118f));
            }
            *(f32x4*)&out[((size_t)b * COUT_ + cout) * HW_ + (size_t)gy * W_ +
                          x0 + kgrp * 4] = gv;
        }
    }
}

extern "C" void kernel_launch(void* const* d_in, const int* in_sizes, int n_in,
                              void* d_out, int out_size, void* d_ws, size_t ws_size,
                              hipStream_t stream) {
    const float* x  = (const float*)d_in[0];
    const float* pf = (const float*)d_in[1];
    const float* of = (const float*)d_in[2];
    float* out = (float*)d_out;

    unsigned short* sa  = (unsigned short*)d_ws;                       // 154,140,672 B
    unsigned short* ofb = (unsigned short*)((char*)d_ws + 154140672);  // + 165,888 B

    prep_ofb<<<324, 256, 0, stream>>>(of, ofb);
    sa_kernel<<<B_ * P_, 256, 0, stream>>>(x, pf, sa);
    conv2_mfma<<<B_ * P_, 256, 0, stream>>>(sa, ofb, out);
}

// Round 6
// 434.258 us; speedup vs baseline: 2.0617x; 1.0688x over previous
//
#include <hip/hip_runtime.h>
#include <hip/hip_bf16.h>

#define B_    16
#define C_    96
#define H_    224
#define W_    224
#define COUT_ 96
#define GH_   14
#define GW_   14
#define P_    196          // GH_*GW_
#define HW_   (H_*W_)      // 50176
#define NCH_  12           // 8-channel chunks

typedef __attribute__((ext_vector_type(8))) unsigned short ushort8;
typedef __attribute__((ext_vector_type(8))) short        short8;   // MFMA bf16x8 operand
typedef __attribute__((ext_vector_type(4))) float        f32x4;

__device__ __forceinline__ unsigned short f2bf(float f) {
    union { __hip_bfloat16 h; unsigned short u; } cv;
    cv.h = __float2bfloat16(f);
    return cv.u;
}

// ---------------------------------------------------------------------------
// Kernel 0: output_filters (COUT, C, 3, 3) f32 -> ofb[tap][cout][c] bf16
// ---------------------------------------------------------------------------
__global__ __launch_bounds__(256) void prep_ofb(const float* __restrict__ of,
                                                unsigned short* __restrict__ ofb) {
    int idx = blockIdx.x * 256 + threadIdx.x;      // 9*96*96 = 82944
    if (idx < 9 * 96 * 96) {
        int tap = idx / (96 * 96);
        int r   = idx % (96 * 96);
        int cout = r / 96, c = r % 96;
        ofb[idx] = f2bf(of[((size_t)cout * 96 + c) * 9 + tap]);
    }
}

// ---------------------------------------------------------------------------
// Kernel 1: per-patch depthwise 3x3 (patch-local zero padding).
// x: (B,C,H,W) f32 -> sa: (B, 12, H, W, 8) bf16  (8-ch chunk planes).
// Block = (b,patch), thread = pixel. 16 KB dbuf LDS, 1 barrier/chunk.
// (R5-proven: ~107 us, near the 86 us traffic floor. Unchanged.)
// ---------------------------------------------------------------------------
__global__ __launch_bounds__(256) void sa_kernel(const float* __restrict__ x,
                                                 const float* __restrict__ pf,
                                                 unsigned short* __restrict__ sa) {
    int bid   = blockIdx.x;
    int patch = bid % P_;
    int b     = bid / P_;
    int gh = patch / GW_, gw = patch % GW_;
    int t  = threadIdx.x;
    int py = t >> 4, px = t & 15;
    int y  = gh * 16 + py, xx = gw * 16 + px;

    __shared__ float xs[2][8][256];    // 16 KB double-buffered x slice

    const float* xp0 = x + (size_t)b * C_ * HW_ + (size_t)y * W_ + xx;

    float lf[8];
    #pragma unroll
    for (int ch = 0; ch < 8; ++ch) lf[ch] = xp0[(size_t)ch * HW_];

    for (int cc = 0; cc < NCH_; ++cc) {
        int buf = cc & 1;
        #pragma unroll
        for (int ch = 0; ch < 8; ++ch) xs[buf][ch][t] = lf[ch];
        __syncthreads();
        if (cc < NCH_ - 1) {
            #pragma unroll
            for (int ch = 0; ch < 8; ++ch)
                lf[ch] = xp0[(size_t)((cc + 1) * 8 + ch) * HW_];
        }

        ushort8 v;
        #pragma unroll
        for (int ch = 0; ch < 8; ++ch) {
            const float* wgt = pf + ((size_t)(cc * 8 + ch) * P_ + patch) * 9;  // uniform -> s_load
            float a = 0.f;
            #pragma unroll
            for (int dy = -1; dy <= 1; ++dy) {
                int yy = py + dy;
                if ((unsigned)yy < 16u) {
                    #pragma unroll
                    for (int dx = -1; dx <= 1; ++dx) {
                        int xq = px + dx;
                        if ((unsigned)xq < 16u)
                            a = fmaf(xs[buf][ch][yy * 16 + xq],
                                     wgt[(dy + 1) * 3 + (dx + 1)], a);
                    }
                }
            }
            v[ch] = f2bf(a);
        }
        // lanes consecutive in x -> 16 B/lane fully coalesced
        *(ushort8*)&sa[(((size_t)(b * NCH_ + cc) * H_ + y) * W_ + xx) * 8] = v;
    }
}

// ---------------------------------------------------------------------------
// Kernel 2: dense 3x3 conv as implicit GEMM (M=256 px, N=96, K=864) + GELU.
// sa: (B,12,H,W,8) bf16; ofb: [tap][cout][c] bf16; out: (B,COUT,H,W) f32.
// Per 32-ch group: reg-stage halo tile -> padded LDS (stride 40 ushorts,
// measured ~free banks), double-buffered, ONE barrier per group.
// R6 change: tap loop FULLY UNROLLED -> 216-MFMA scheduling window per group
// so LLVM pipelines the 54 B-loads + 36 A-reads ahead of the MFMAs.
// ---------------------------------------------------------------------------
__global__ __launch_bounds__(256, 2) void conv2_mfma(const unsigned short* __restrict__ sa,
                                                     const unsigned short* __restrict__ ofb,
                                                     float* __restrict__ out) {
    // XCD-aware swizzle (3136 % 8 == 0 -> bijective)
    int bid0 = blockIdx.x;
    int bid  = (bid0 % 8) * (3136 / 8) + bid0 / 8;
    int patch = bid % P_;
    int b     = bid / P_;
    int gh = patch / GW_, gw = patch % GW_;
    int y0 = gh * 16, x0 = gw * 16;

    int t = threadIdx.x;
    int w = t >> 6, l = t & 63;
    int mrow = l & 15, kgrp = l >> 4;

    __shared__ ushort8 at8[2][1620];        // 2 x 324 px x 40 ushort = 51840 B

    ushort8 r[6];                           // staged tiles in flight (24 VGPR)

    // ---- load one 32-ch group's 18x18 halo (4 chunk-planes) into regs ----
    auto LOADG = [&](int g) {
        #pragma unroll
        for (int i = 0; i < 6; ++i) {
            int v = t + i * 256;            // 1296 tasks = 4 chunks x 324 px
            if (v < 1296) {
                int ccl = v / 324, hpx = v % 324;
                int gy = y0 - 1 + hpx / 18, gx = x0 - 1 + hpx % 18;
                ushort8 val = {0, 0, 0, 0, 0, 0, 0, 0};
                if ((unsigned)gy < (unsigned)H_ && (unsigned)gx < (unsigned)W_)
                    val = *(const ushort8*)&sa[(((size_t)(b * NCH_ + g * 4 + ccl) * H_ + gy)
                                               * W_ + gx) * 8];
                r[i] = val;
            }
        }
    };
    auto WRITEG = [&](int g) {
        unsigned short* atw = (unsigned short*)at8[g & 1];
        #pragma unroll
        for (int i = 0; i < 6; ++i) {
            int v = t + i * 256;
            if (v < 1296) {
                int ccl = v / 324, hpx = v % 324;
                *(ushort8*)&atw[hpx * 40 + ccl * 8] = r[i];
            }
        }
    };

    f32x4 acc[4][6];
    #pragma unroll
    for (int mi = 0; mi < 4; ++mi)
        #pragma unroll
        for (int ni = 0; ni < 6; ++ni)
            acc[mi][ni] = (f32x4)0.f;

    LOADG(0);
    #pragma unroll 1
    for (int g = 0; g < 3; ++g) {
        WRITEG(g);                          // waits (auto vmcnt) on LOADG(g)
        __syncthreads();                    // tile g visible to all waves
        if (g < 2) LOADG(g + 1);            // overlap next loads with MFMA
        const unsigned short* atg = (const unsigned short*)at8[g & 1];

        #pragma unroll                      // FULL unroll: one big scheduling window
        for (int tap = 0; tap < 9; ++tap) {
            int ky = tap / 3, kx = tap % 3;
            short8 af[4];
            #pragma unroll
            for (int mi = 0; mi < 4; ++mi)
                af[mi] = *(const short8*)&atg[((w * 4 + mi + ky) * 18 + kx + mrow) * 40
                                              + kgrp * 8];
            const unsigned short* bofs = ofb + tap * (96 * 96) + g * 32 + kgrp * 8;
            #pragma unroll
            for (int ni = 0; ni < 6; ++ni) {
                short8 bf = *(const short8*)&bofs[(ni * 16 + mrow) * 96];
                #pragma unroll
                for (int mi = 0; mi < 4; ++mi)
                    acc[mi][ni] = __builtin_amdgcn_mfma_f32_16x16x32_bf16(
                        af[mi], bf, acc[mi][ni], 0, 0, 0);
            }
        }
    }

    // ---- epilogue: exact GELU + f32x4 stores ----
    #pragma unroll
    for (int mi = 0; mi < 4; ++mi) {
        int gy = y0 + w * 4 + mi;
        #pragma unroll
        for (int ni = 0; ni < 6; ++ni) {
            int cout = ni * 16 + mrow;
            f32x4 gv;
            #pragma unroll
            for (int j = 0; j < 4; ++j) {
                float vv = acc[mi][ni][j];
                gv[j] = 0.5f * vv * (1.0f + erff(vv * 0.70710678118f));
            }
            *(f32x4*)&out[((size_t)b * COUT_ + cout) * HW_ + (size_t)gy * W_ +
                          x0 + kgrp * 4] = gv;
        }
    }
}

extern "C" void kernel_launch(void* const* d_in, const int* in_sizes, int n_in,
                              void* d_out, int out_size, void* d_ws, size_t ws_size,
                              hipStream_t stream) {
    const float* x  = (const float*)d_in[0];
    const float* pf = (const float*)d_in[1];
    const float* of = (const float*)d_in[2];
    float* out = (float*)d_out;

    unsigned short* sa  = (unsigned short*)d_ws;                       // 154,140,672 B
    unsigned short* ofb = (unsigned short*)((char*)d_ws + 154140672);  // + 165,888 B

    prep_ofb<<<324, 256, 0, stream>>>(of, ofb);
    sa_kernel<<<B_ * P_, 256, 0, stream>>>(x, pf, sa);
    conv2_mfma<<<B_ * P_, 256, 0, stream>>>(sa, ofb, out);
}